// Round 12
// baseline (463.023 us; speedup 1.0000x reference)
//
#include <hip/hip_runtime.h>
#include <hip/hip_bf16.h>
#include <cmath>
#include <cstddef>

#define N 8192
#define D 256
#define BIR 128                 // rows per block tile (and cols per pair-block)
#define NPAIR 2080              // #{(ti,tjj): 0<=ti<=tjj<64} = 8 * 260

typedef __attribute__((ext_vector_type(8))) short short8;   // 8 bf16 = one MFMA A/B frag
typedef __attribute__((ext_vector_type(4))) float float4v;  // MFMA C/D frag

#define U64MAX 0xFFFFFFFFFFFFFFFFull

__device__ inline ushort f2bf(float x) {
    __hip_bfloat16 h = __float2bfloat16(x);
    return __builtin_bit_cast(ushort, h);
}
__device__ inline float bf2f(ushort u) {
    __hip_bfloat16 h = __builtin_bit_cast(__hip_bfloat16, u);
    return __bfloat162float(h);
}

// sortable pack: (monotone-uint(key) << 32) | idx  -> u64 min == lex (key,idx) argmin,
// lowest-idx tie-break. Identical semantics to all prior passing revs.
__device__ inline unsigned long long packKI(float k, int idx) {
    unsigned u = __float_as_uint(k);
    u = (u & 0x80000000u) ? ~u : (u | 0x80000000u);
    return ((unsigned long long)u << 32) | (unsigned)idx;
}
__device__ inline unsigned long long min64(unsigned long long a, unsigned long long b) {
    return a < b ? a : b;
}

// ============================================================================
// Frag-tiled bf16 layout (unchanged): frag for (16-row group g, k-chunk k, lane)
// at ushort offset (g*8 + k)*512 + lane*8 -> wave frag load = uniform base +
// lane*16B: one coalesced 1 KB dwordx4.
// ============================================================================

// ---------------- K1: slim prep — sqnorm, frag-tiled bf16 hi/lo split, M init ----
// grid MUST be 1024 x 256 (phase C uses exactly 4096 waves, one 16x32 tile each).
__global__ void prep_kernel(const float4* __restrict__ a,
                            float* __restrict__ sq,
                            ushort* __restrict__ Ehi, ushort* __restrict__ Elo,
                            unsigned long long* __restrict__ M) {
    const int gsz = gridDim.x * blockDim.x;          // 262144, multiple of 64
    const int g0 = blockIdx.x * blockDim.x + threadIdx.x;
    const int total = N * D / 4;                     // 524288 float4

    // phase A: per-row sqnorm (one row per wave per iter: 64 float4 = 1 row)
    for (int idx = g0; idx < total; idx += gsz) {
        float4 v = a[idx];
        float s = v.x * v.x + v.y * v.y + v.z * v.z + v.w * v.w;
        #pragma unroll
        for (int off = 32; off; off >>= 1) s += __shfl_down(s, off);
        if ((threadIdx.x & 63) == 0) sq[idx >> 6] = s;
    }

    // phase C: frag-tiled hi/lo split. One wave per (r16, ktc) tile of 16 rows x 32 k.
    {
        const int w = g0 >> 6;           // global wave id, 0..4095
        if (w < 4096) {
            const int lane = threadIdx.x & 63;
            const int tx = lane & 15;
            const int q  = lane >> 4;
            const int r16 = w >> 3;      // 0..511
            const int ktc = w & 7;       // 0..7
            const int row = r16 * 16 + tx;
            const float4 v0 = a[row * 64 + ktc * 8 + q * 2];
            const float4 v1 = a[row * 64 + ktc * 8 + q * 2 + 1];
            float e[8] = {v0.x, v0.y, v0.z, v0.w, v1.x, v1.y, v1.z, v1.w};
            short8 hs, ls;
            #pragma unroll
            for (int j = 0; j < 8; j++) {
                ushort h = f2bf(e[j]);
                ushort l = f2bf(e[j] - bf2f(h));
                hs[j] = (short)h;
                ls[j] = (short)l;
            }
            const size_t off = (size_t)(r16 * 8 + ktc) * 512 + lane * 8;
            *(short8*)&Ehi[off] = hs;
            *(short8*)&Elo[off] = ls;
        }
    }
    // M init
    for (int i = g0; i < N; i += gsz) M[i] = 0xFFFFFFFFFFFFFFFFull;
}

// ---------------- K2: spill-free pair-blocks 128x128 (two sequential 64-col halves) ----
// Each half = the COMPLETE round-9 unit (verified 96us): K-loop (12 batched
// loads/chunk -> sched_barrier -> 24 MFMAs -> sched_barrier, offsets +1024/chunk)
// followed immediately by the full r9 epilogue (shuffle chains), results packed
// (packKI == lex (key,idx), r10-validated) into per-half LDS slots. NO u64 state
// held across halves (r10's spill cause). Amortized once per pair: decode,
// hostAp (4x int4 loads/wave instead of 16 scalar), sq/host staging, final
// atomics, one launch. Enumeration: bands grouped by 16, col-major (L2-hot,
// FETCH 16.6MB heritage). Universal (jg<=ig) mask; keys/MFMA order unchanged
// -> identical argmin indices.
__launch_bounds__(256, 4)
__global__ void argmin_sym(const ushort* __restrict__ Ehi, const ushort* __restrict__ Elo,
                           const int* __restrict__ host, const float* __restrict__ sq,
                           unsigned long long* __restrict__ M) {
    // XCD swizzle (2080 = 8*260, bijective)
    const int b0 = blockIdx.x;
    const int b = (b0 & 7) * (NPAIR / 8) + (b0 >> 3);

    // decode b -> (group g of 16 bands, column dd, band-in-group i), col-major
    // (verified in round 10: absmax 0.0). Group sizes 904/648/392/136.
    int g, p;
    if (b < 904)       { g = 0; p = b; }
    else if (b < 1552) { g = 1; p = b - 904; }
    else if (b < 1944) { g = 2; p = b - 1552; }
    else               { g = 3; p = b - 1944; }
    int dd, i;
    if (p >= 136) {
        dd = 16 + ((p - 136) >> 4);
        i = (p - 136) & 15;
    } else {
        int m = (int)((sqrtf(8.0f * (float)p + 1.0f) - 1.0f) * 0.5f);
        while ((m + 1) * (m + 2) / 2 <= p) m++;
        while (m * (m + 1) / 2 > p) m--;
        dd = m; i = p - m * (m + 1) / 2;
    }
    const int ti  = 16 * g + i;     // 128-row band
    const int tjj = 16 * g + dd;    // 128-col pair, tjj >= ti

    __shared__ float sqA_s[BIR];
    __shared__ float sqB_s[BIR];                    // 128 cols (both halves)
    __shared__ int   hostB_s[BIR];
    __shared__ unsigned long long rowU[4 * BIR];    // [il][h][wcol]
    __shared__ unsigned long long colU[2 * BIR];    // [jl][wrow] (jl unique per half)

    const int ib0 = ti * BIR;
    const int jb0 = tjj * BIR;
    const int tid = threadIdx.x;
    const int lane = tid & 63;
    const int wave = tid >> 6;      // 0..3
    const int wrow = wave >> 1;     // 0..1  (64-row half)
    const int wcol = wave & 1;      // 0..1  (32-col half within each 64-col half)
    const int tx = lane & 15;       // 0..15
    const int q  = lane >> 4;       // 0..3

    // stage epilogue scalars once for the whole pair
    if (tid < BIR) {
        sqA_s[tid] = sq[ib0 + tid];
        sqB_s[tid] = sq[jb0 + tid];
        hostB_s[tid] = host[jb0 + tid];
    }

    // hostA packed per rt: ONE int4 load per rt (was 16 scalar loads)
    unsigned hostAp[4];
    #pragma unroll
    for (int rt = 0; rt < 4; rt++) {
        const int4 hv = *(const int4*)&host[ib0 + wrow * 64 + rt * 16 + q * 4];
        hostAp[rt] = ((unsigned)hv.x & 0xFFu) | (((unsigned)hv.y & 0xFFu) << 8) |
                     (((unsigned)hv.z & 0xFFu) << 16) | (((unsigned)hv.w & 0xFFu) << 24);
    }
    __syncthreads();   // staging visible before half-0 epilogue reads

    const int pA = (ib0 >> 4) + wrow * 4;   // + rt (0..3)
    const int lo16 = lane * 16;             // byte offset of lane's 16B frag
    const char* EhiB = (const char*)Ehi;
    const char* EloB = (const char*)Elo;

    float4v acc[4][2];   // [rt][ct]
    short8 aH[4], aL[4], bH[2], bL[2];

    #pragma unroll
    for (int h = 0; h < 2; h++) {
        // ---- offsets for this half ----
        int obA[4], obB[2];
        #pragma unroll
        for (int rt = 0; rt < 4; rt++) obA[rt] = ((pA + rt) * 8) * 1024 + lo16;
        #pragma unroll
        for (int ct = 0; ct < 2; ct++)
            obB[ct] = ((tjj * 8 + h * 4 + wcol * 2 + ct) * 8) * 1024 + lo16;
        #pragma unroll
        for (int rt = 0; rt < 4; rt++)
            #pragma unroll
            for (int ct = 0; ct < 2; ct++) acc[rt][ct] = (float4v)(0.0f);

        // ---- K-loop (byte-identical schedule to round 9) ----
        #pragma unroll
        for (int k = 0; k < 8; k++) {
            #pragma unroll
            for (int rt = 0; rt < 4; rt++) {
                aH[rt] = *(const short8*)(EhiB + obA[rt]);
                aL[rt] = *(const short8*)(EloB + obA[rt]);
            }
            #pragma unroll
            for (int ct = 0; ct < 2; ct++) {
                bH[ct] = *(const short8*)(EhiB + obB[ct]);
                bL[ct] = *(const short8*)(EloB + obB[ct]);
            }
            #pragma unroll
            for (int rt = 0; rt < 4; rt++) obA[rt] += 1024;
            #pragma unroll
            for (int ct = 0; ct < 2; ct++) obB[ct] += 1024;
            __builtin_amdgcn_sched_barrier(0);   // loads stay above, batched
            #pragma unroll
            for (int rt = 0; rt < 4; rt++)
                #pragma unroll
                for (int ct = 0; ct < 2; ct++)
                    acc[rt][ct] = __builtin_amdgcn_mfma_f32_16x16x32_bf16(aH[rt], bH[ct], acc[rt][ct], 0, 0, 0);
            #pragma unroll
            for (int rt = 0; rt < 4; rt++)
                #pragma unroll
                for (int ct = 0; ct < 2; ct++)
                    acc[rt][ct] = __builtin_amdgcn_mfma_f32_16x16x32_bf16(aH[rt], bL[ct], acc[rt][ct], 0, 0, 0);
            #pragma unroll
            for (int rt = 0; rt < 4; rt++)
                #pragma unroll
                for (int ct = 0; ct < 2; ct++)
                    acc[rt][ct] = __builtin_amdgcn_mfma_f32_16x16x32_bf16(aL[rt], bH[ct], acc[rt][ct], 0, 0, 0);
            __builtin_amdgcn_sched_barrier(0);   // next chunk's loads may not hoist above
        }

        // ---- full epilogue for this half (r9 structure; acc dies here) ----
        // rows side: per lane's 16 rows, min over its 2 ct entries, then over tx
        #pragma unroll
        for (int rt = 0; rt < 4; rt++) {
            unsigned hp = hostAp[rt];
            #pragma unroll
            for (int reg = 0; reg < 4; reg++) {
                const int il = wrow * 64 + rt * 16 + q * 4 + reg;
                const int ig = ib0 + il;
                const int ha = (int)((hp >> (8 * reg)) & 0xFFu);
                float v = 3.0e38f; int ix = 0x7fffffff;
                #pragma unroll
                for (int ct = 0; ct < 2; ct++) {
                    const int jl = h * 64 + wcol * 32 + ct * 16 + tx;
                    const int jg = jb0 + jl;
                    const float key = sqB_s[jl] - 2.0f * acc[rt][ct][reg];
                    const bool masked = (hostB_s[jl] == ha) || (jg <= ig);  // strict upper
                    if (!masked && (key < v || (key == v && jg < ix))) { v = key; ix = jg; }
                }
                #pragma unroll
                for (int s = 1; s < 16; s <<= 1) {
                    float ov = __shfl_xor(v, s);
                    int   oi = __shfl_xor(ix, s);
                    if (ov < v || (ov == v && oi < ix)) { v = ov; ix = oi; }
                }
                if (tx == 0) rowU[il * 4 + h * 2 + wcol] = packKI(v, ix);
            }
        }
        // cols side: per lane's 2 cols of this half, min over 16 rows, reduce over q
        #pragma unroll
        for (int ct = 0; ct < 2; ct++) {
            const int jl = h * 64 + wcol * 32 + ct * 16 + tx;
            const int jg = jb0 + jl;
            const int hb = hostB_s[jl];
            float v = 3.0e38f; int ix = 0x7fffffff;
            #pragma unroll
            for (int rt = 0; rt < 4; rt++) {
                unsigned hp = hostAp[rt];
                #pragma unroll
                for (int reg = 0; reg < 4; reg++) {
                    const int il = wrow * 64 + rt * 16 + q * 4 + reg;
                    const int ig = ib0 + il;
                    const bool masked = ((int)((hp >> (8 * reg)) & 0xFFu) == hb) || (ig >= jg);
                    const float key = sqA_s[il] - 2.0f * acc[rt][ct][reg];
                    if (!masked && (key < v || (key == v && ig < ix))) { v = key; ix = ig; }
                }
            }
            #pragma unroll
            for (int s = 16; s < 64; s <<= 1) {
                float ov = __shfl_xor(v, s);
                int   oi = __shfl_xor(ix, s);
                if (ov < v || (ov == v && oi < ix)) { v = ov; ix = oi; }
            }
            if (q == 0) colU[jl * 2 + wrow] = packKI(v, ix);   // jl unique per half
        }
    }

    // ---- final merge: one atomic per row and per col ----
    __syncthreads();
    if (tid < BIR) {
        unsigned long long r = min64(min64(rowU[tid * 4 + 0], rowU[tid * 4 + 1]),
                                     min64(rowU[tid * 4 + 2], rowU[tid * 4 + 3]));
        atomicMin(&M[ib0 + tid], r);
        atomicMin(&M[jb0 + tid], min64(colU[tid * 2], colU[tid * 2 + 1]));
    }
}

// ---------------- K3: fused output — copy e_actv/e_ap rows + gather e_an ----------------
__global__ void finalize_kernel(const unsigned long long* __restrict__ M,
                                const float4* __restrict__ a, const float4* __restrict__ p,
                                float4* __restrict__ out) {
    const int row = blockIdx.x;
    const int t = threadIdx.x;   // 0..63
    const int o = row * 64 + t;
    const int idx = (int)(unsigned)(M[row] & 0xFFFFFFFFull);
    float4 v = a[idx * 64 + t];
    out[o] = a[o];                         // e_actv copy
    out[(N * 64) + o] = p[o];              // e_ap copy
    out[(2 * N * 64) + o] = v;             // e_an
}

extern "C" void kernel_launch(void* const* d_in, const int* in_sizes, int n_in,
                              void* d_out, int out_size, void* d_ws, size_t ws_size,
                              hipStream_t stream) {
    const float* e_actv = (const float*)d_in[0];
    const float* e_ap   = (const float*)d_in[1];
    const int*   host   = (const int*)d_in[2];
    float* out = (float*)d_out;

    // workspace: M u64[N] | sq f32[N] | Ehi bf16[N*D] | Elo bf16[N*D]  (~8.3 MB)
    unsigned long long* M = (unsigned long long*)d_ws;
    float*  sq  = (float*)(M + N);
    ushort* Ehi = (ushort*)(sq + N);
    ushort* Elo = Ehi + (size_t)N * D;

    prep_kernel<<<1024, 256, 0, stream>>>(
        (const float4*)e_actv, sq, Ehi, Elo, M);
    argmin_sym<<<NPAIR, 256, 0, stream>>>(Ehi, Elo, host, sq, M);
    finalize_kernel<<<N, 64, 0, stream>>>(
        M, (const float4*)e_actv, (const float4*)e_ap, (float4*)out);
}

// Round 13
// 176.421 us; speedup vs baseline: 2.6245x; 2.6245x over previous
//
#include <hip/hip_runtime.h>
#include <hip/hip_bf16.h>
#include <cmath>
#include <cstddef>

#define N 8192
#define D 256
#define BIR 128                 // rows (and cols) per pair-block
#define NPAIR 2080              // #{(ti,tjj): 0<=ti<=tjj<64} = 8 * 260

typedef __attribute__((ext_vector_type(8))) short short8;   // 8 bf16 = one MFMA A/B frag
typedef __attribute__((ext_vector_type(4))) float float4v;  // MFMA C/D frag

#define U64MAX 0xFFFFFFFFFFFFFFFFull

__device__ inline ushort f2bf(float x) {
    __hip_bfloat16 h = __float2bfloat16(x);
    return __builtin_bit_cast(ushort, h);
}
__device__ inline float bf2f(ushort u) {
    __hip_bfloat16 h = __builtin_bit_cast(__hip_bfloat16, u);
    return __bfloat162float(h);
}

// sortable pack: (monotone-uint(key) << 32) | idx  -> u64 min == lex (key,idx) argmin,
// lowest-idx tie-break. Identical semantics to all prior passing revs.
__device__ inline unsigned long long packKI(float k, int idx) {
    unsigned u = __float_as_uint(k);
    u = (u & 0x80000000u) ? ~u : (u | 0x80000000u);
    return ((unsigned long long)u << 32) | (unsigned)idx;
}
__device__ inline unsigned long long min64(unsigned long long a, unsigned long long b) {
    return a < b ? a : b;
}

// ============================================================================
// Frag-tiled bf16 layout (unchanged): frag for (16-row group g, k-chunk k, lane)
// at ushort offset (g*8 + k)*512 + lane*8 -> wave frag load = uniform base +
// lane*16B: one coalesced 1 KB dwordx4.
// ============================================================================

// ---------------- K1: slim prep — sqnorm, frag-tiled bf16 hi/lo split, M init ----
// grid MUST be 1024 x 256 (phase C uses exactly 4096 waves, one 16x32 tile each).
__global__ void prep_kernel(const float4* __restrict__ a,
                            float* __restrict__ sq,
                            ushort* __restrict__ Ehi, ushort* __restrict__ Elo,
                            unsigned long long* __restrict__ M) {
    const int gsz = gridDim.x * blockDim.x;          // 262144, multiple of 64
    const int g0 = blockIdx.x * blockDim.x + threadIdx.x;
    const int total = N * D / 4;                     // 524288 float4

    // phase A: per-row sqnorm (one row per wave per iter: 64 float4 = 1 row)
    for (int idx = g0; idx < total; idx += gsz) {
        float4 v = a[idx];
        float s = v.x * v.x + v.y * v.y + v.z * v.z + v.w * v.w;
        #pragma unroll
        for (int off = 32; off; off >>= 1) s += __shfl_down(s, off);
        if ((threadIdx.x & 63) == 0) sq[idx >> 6] = s;
    }

    // phase C: frag-tiled hi/lo split. One wave per (r16, ktc) tile of 16 rows x 32 k.
    {
        const int w = g0 >> 6;           // global wave id, 0..4095
        if (w < 4096) {
            const int lane = threadIdx.x & 63;
            const int tx = lane & 15;
            const int q  = lane >> 4;
            const int r16 = w >> 3;      // 0..511
            const int ktc = w & 7;       // 0..7
            const int row = r16 * 16 + tx;
            const float4 v0 = a[row * 64 + ktc * 8 + q * 2];
            const float4 v1 = a[row * 64 + ktc * 8 + q * 2 + 1];
            float e[8] = {v0.x, v0.y, v0.z, v0.w, v1.x, v1.y, v1.z, v1.w};
            short8 hs, ls;
            #pragma unroll
            for (int j = 0; j < 8; j++) {
                ushort h = f2bf(e[j]);
                ushort l = f2bf(e[j] - bf2f(h));
                hs[j] = (short)h;
                ls[j] = (short)l;
            }
            const size_t off = (size_t)(r16 * 8 + ktc) * 512 + lane * 8;
            *(short8*)&Ehi[off] = hs;
            *(short8*)&Elo[off] = ls;
        }
    }
    // M init
    for (int i = g0; i < N; i += gsz) M[i] = 0xFFFFFFFFFFFFFFFFull;
}

// ---------------- K2: WIDE pair-blocks — 512 threads, 8 waves, 128x128 in one pass ----
// Each of the 8 waves runs the round-9 per-wave unit UNCHANGED (same K-loop:
// 12 batched loads/chunk -> sched_barrier -> 24 MFMAs -> sched_barrier, offsets
// +1024/chunk; same epilogue shuffle chains). wrow in {0,1}, wcol in {0..3}
// covers the full 128x128 pair in parallel — NO sequential fusion, NO enlarged
// scheduling region (r10/r12's spill vector). Amortized vs r9: half the blocks
// (2080), one decode/staging/atomic pass per pair; B frags L1-shared by the 2
// waves per wcol, A frags by the 4 waves per wrow. Coverage: (ti,tjj) with
// tjj>=ti in 128-col units == r9's tj>=2ti set; universal (jg<=ig) mask.
// Keys/masks/MFMA order identical to r9 -> identical argmin indices.
__launch_bounds__(512, 4)
__global__ void argmin_sym(const ushort* __restrict__ Ehi, const ushort* __restrict__ Elo,
                           const int* __restrict__ host, const float* __restrict__ sq,
                           unsigned long long* __restrict__ M) {
    // XCD swizzle (2080 = 8*260, bijective)
    const int b0 = blockIdx.x;
    const int b = (b0 & 7) * (NPAIR / 8) + (b0 >> 3);

    // decode b -> (group g of 16 bands, column dd, band-in-group i), col-major
    // (numerically verified in rounds 10/12: absmax 0.0). Group sizes 904/648/392/136.
    int g, p;
    if (b < 904)       { g = 0; p = b; }
    else if (b < 1552) { g = 1; p = b - 904; }
    else if (b < 1944) { g = 2; p = b - 1552; }
    else               { g = 3; p = b - 1944; }
    int dd, i;
    if (p >= 136) {
        dd = 16 + ((p - 136) >> 4);
        i = (p - 136) & 15;
    } else {
        int m = (int)((sqrtf(8.0f * (float)p + 1.0f) - 1.0f) * 0.5f);
        while ((m + 1) * (m + 2) / 2 <= p) m++;
        while (m * (m + 1) / 2 > p) m--;
        dd = m; i = p - m * (m + 1) / 2;
    }
    const int ti  = 16 * g + i;     // 128-row band
    const int tjj = 16 * g + dd;    // 128-col pair, tjj >= ti

    __shared__ float sqA_s[BIR];
    __shared__ float sqB_s[BIR];
    __shared__ int   hostB_s[BIR];
    __shared__ unsigned long long rowU[4 * BIR];   // [il][wcol]
    __shared__ unsigned long long colU[2 * BIR];   // [jl][wrow]

    const int ib0 = ti * BIR;
    const int jb0 = tjj * BIR;
    const int tid = threadIdx.x;    // 0..511
    const int lane = tid & 63;
    const int wave = tid >> 6;      // 0..7
    const int wrow = wave >> 2;     // 0..1  (64-row half)
    const int wcol = wave & 3;      // 0..3  (32-col quarter)
    const int tx = lane & 15;       // 0..15
    const int q  = lane >> 4;       // 0..3

    // stage epilogue scalars once per pair
    if (tid < BIR) {
        sqA_s[tid] = sq[ib0 + tid];
        sqB_s[tid] = sq[jb0 + tid];
        hostB_s[tid] = host[jb0 + tid];
    }

    // hostA packed per rt: one int4 load per rt (verified in r12)
    unsigned hostAp[4];
    #pragma unroll
    for (int rt = 0; rt < 4; rt++) {
        const int4 hv = *(const int4*)&host[ib0 + wrow * 64 + rt * 16 + q * 4];
        hostAp[rt] = ((unsigned)hv.x & 0xFFu) | (((unsigned)hv.y & 0xFFu) << 8) |
                     (((unsigned)hv.z & 0xFFu) << 16) | (((unsigned)hv.w & 0xFFu) << 24);
    }

    float4v acc[4][2];   // [rt][ct] — 32 f32/lane (identical to r9)
    #pragma unroll
    for (int rt = 0; rt < 4; rt++)
        #pragma unroll
        for (int ct = 0; ct < 2; ct++) acc[rt][ct] = (float4v)(0.0f);

    const int pA = (ib0 >> 4) + wrow * 4;   // + rt (0..3)
    const int lo16 = lane * 16;
    const char* EhiB = (const char*)Ehi;
    const char* EloB = (const char*)Elo;

    int obA[4], obB[2];
    #pragma unroll
    for (int rt = 0; rt < 4; rt++) obA[rt] = ((pA + rt) * 8) * 1024 + lo16;
    #pragma unroll
    for (int ct = 0; ct < 2; ct++) obB[ct] = ((tjj * 8 + wcol * 2 + ct) * 8) * 1024 + lo16;

    short8 aH[4], aL[4], bH[2], bL[2];

    // ---- K-loop: byte-identical schedule to round 9 (verified 96us) ----
    #pragma unroll
    for (int k = 0; k < 8; k++) {
        #pragma unroll
        for (int rt = 0; rt < 4; rt++) {
            aH[rt] = *(const short8*)(EhiB + obA[rt]);
            aL[rt] = *(const short8*)(EloB + obA[rt]);
        }
        #pragma unroll
        for (int ct = 0; ct < 2; ct++) {
            bH[ct] = *(const short8*)(EhiB + obB[ct]);
            bL[ct] = *(const short8*)(EloB + obB[ct]);
        }
        #pragma unroll
        for (int rt = 0; rt < 4; rt++) obA[rt] += 1024;
        #pragma unroll
        for (int ct = 0; ct < 2; ct++) obB[ct] += 1024;
        __builtin_amdgcn_sched_barrier(0);   // loads stay above, batched
        #pragma unroll
        for (int rt = 0; rt < 4; rt++)
            #pragma unroll
            for (int ct = 0; ct < 2; ct++)
                acc[rt][ct] = __builtin_amdgcn_mfma_f32_16x16x32_bf16(aH[rt], bH[ct], acc[rt][ct], 0, 0, 0);
        #pragma unroll
        for (int rt = 0; rt < 4; rt++)
            #pragma unroll
            for (int ct = 0; ct < 2; ct++)
                acc[rt][ct] = __builtin_amdgcn_mfma_f32_16x16x32_bf16(aH[rt], bL[ct], acc[rt][ct], 0, 0, 0);
        #pragma unroll
        for (int rt = 0; rt < 4; rt++)
            #pragma unroll
            for (int ct = 0; ct < 2; ct++)
                acc[rt][ct] = __builtin_amdgcn_mfma_f32_16x16x32_bf16(aL[rt], bH[ct], acc[rt][ct], 0, 0, 0);
        __builtin_amdgcn_sched_barrier(0);   // next chunk's loads may not hoist above
    }

    // ---- epilogue (r9 structure; jl now spans 128 via wcol 0..3) ----
    __syncthreads();   // orders staging before LDS reads; acc complete per wave

    // rows side: per lane's 16 rows, min over its 2 ct entries, then over tx
    #pragma unroll
    for (int rt = 0; rt < 4; rt++) {
        unsigned hp = hostAp[rt];
        #pragma unroll
        for (int reg = 0; reg < 4; reg++) {
            const int il = wrow * 64 + rt * 16 + q * 4 + reg;
            const int ig = ib0 + il;
            const int ha = (int)((hp >> (8 * reg)) & 0xFFu);
            float v = 3.0e38f; int ix = 0x7fffffff;
            #pragma unroll
            for (int ct = 0; ct < 2; ct++) {
                const int jl = wcol * 32 + ct * 16 + tx;
                const int jg = jb0 + jl;
                const float key = sqB_s[jl] - 2.0f * acc[rt][ct][reg];
                const bool masked = (hostB_s[jl] == ha) || (jg <= ig);   // strict upper: i<j
                if (!masked && (key < v || (key == v && jg < ix))) { v = key; ix = jg; }
            }
            #pragma unroll
            for (int s = 1; s < 16; s <<= 1) {
                float ov = __shfl_xor(v, s);
                int   oi = __shfl_xor(ix, s);
                if (ov < v || (ov == v && oi < ix)) { v = ov; ix = oi; }
            }
            if (tx == 0) rowU[il * 4 + wcol] = packKI(v, ix);
        }
    }

    // cols side: per lane's 2 cols, min over 16 rows, reduce over q
    #pragma unroll
    for (int ct = 0; ct < 2; ct++) {
        const int jl = wcol * 32 + ct * 16 + tx;
        const int jg = jb0 + jl;
        const int hb = hostB_s[jl];
        float v = 3.0e38f; int ix = 0x7fffffff;
        #pragma unroll
        for (int rt = 0; rt < 4; rt++) {
            unsigned hp = hostAp[rt];
            #pragma unroll
            for (int reg = 0; reg < 4; reg++) {
                const int il = wrow * 64 + rt * 16 + q * 4 + reg;
                const int ig = ib0 + il;
                const bool masked = ((int)((hp >> (8 * reg)) & 0xFFu) == hb) || (ig >= jg);
                const float key = sqA_s[il] - 2.0f * acc[rt][ct][reg];
                if (!masked && (key < v || (key == v && ig < ix))) { v = key; ix = ig; }
            }
        }
        #pragma unroll
        for (int s = 16; s < 64; s <<= 1) {
            float ov = __shfl_xor(v, s);
            int   oi = __shfl_xor(ix, s);
            if (ov < v || (ov == v && oi < ix)) { v = ov; ix = oi; }
        }
        if (q == 0) colU[jl * 2 + wrow] = packKI(v, ix);
    }

    // ---- final merge: one atomic per row and per col ----
    __syncthreads();
    if (tid < BIR) {
        unsigned long long r = min64(min64(rowU[tid * 4 + 0], rowU[tid * 4 + 1]),
                                     min64(rowU[tid * 4 + 2], rowU[tid * 4 + 3]));
        atomicMin(&M[ib0 + tid], r);
        atomicMin(&M[jb0 + tid], min64(colU[tid * 2], colU[tid * 2 + 1]));
    }
}

// ---------------- K3: fused output — copy e_actv/e_ap rows + gather e_an ----------------
__global__ void finalize_kernel(const unsigned long long* __restrict__ M,
                                const float4* __restrict__ a, const float4* __restrict__ p,
                                float4* __restrict__ out) {
    const int row = blockIdx.x;
    const int t = threadIdx.x;   // 0..63
    const int o = row * 64 + t;
    const int idx = (int)(unsigned)(M[row] & 0xFFFFFFFFull);
    float4 v = a[idx * 64 + t];
    out[o] = a[o];                         // e_actv copy
    out[(N * 64) + o] = p[o];              // e_ap copy
    out[(2 * N * 64) + o] = v;             // e_an
}

extern "C" void kernel_launch(void* const* d_in, const int* in_sizes, int n_in,
                              void* d_out, int out_size, void* d_ws, size_t ws_size,
                              hipStream_t stream) {
    const float* e_actv = (const float*)d_in[0];
    const float* e_ap   = (const float*)d_in[1];
    const int*   host   = (const int*)d_in[2];
    float* out = (float*)d_out;

    // workspace: M u64[N] | sq f32[N] | Ehi bf16[N*D] | Elo bf16[N*D]  (~8.3 MB)
    unsigned long long* M = (unsigned long long*)d_ws;
    float*  sq  = (float*)(M + N);
    ushort* Ehi = (ushort*)(sq + N);
    ushort* Elo = Ehi + (size_t)N * D;

    prep_kernel<<<1024, 256, 0, stream>>>(
        (const float4*)e_actv, sq, Ehi, Elo, M);
    argmin_sym<<<NPAIR, 512, 0, stream>>>(Ehi, Elo, host, sq, M);
    finalize_kernel<<<N, 64, 0, stream>>>(
        M, (const float4*)e_actv, (const float4*)e_ap, (float4*)out);
}

// Round 15
// 166.098 us; speedup vs baseline: 2.7876x; 1.0622x over previous
//
#include <hip/hip_runtime.h>
#include <hip/hip_bf16.h>
#include <cmath>
#include <cstddef>

#define N 8192
#define D 256
#define BIR 128                 // rows per block tile
#define BJC 64                  // cols per block tile
#define NBLK 4160               // #{(ti,tj): ti<64, 2ti<=tj<128} = 8 * 520

typedef __attribute__((ext_vector_type(8))) short short8;   // 8 bf16 = one MFMA A/B frag
typedef __attribute__((ext_vector_type(4))) float float4v;  // MFMA C/D frag

__device__ inline ushort f2bf(float x) {
    __hip_bfloat16 h = __float2bfloat16(x);
    return __builtin_bit_cast(ushort, h);
}
__device__ inline float bf2f(ushort u) {
    __hip_bfloat16 h = __builtin_bit_cast(__hip_bfloat16, u);
    return __bfloat162float(h);
}

// sortable pack: (monotone-uint(key) << 32) | idx  -> atomicMin == argmin, lowest-idx tie-break
__device__ inline unsigned long long packKI(float k, int idx) {
    unsigned u = __float_as_uint(k);
    u = (u & 0x80000000u) ? ~u : (u | 0x80000000u);
    return ((unsigned long long)u << 32) | (unsigned)idx;
}

// ============================================================================
// Frag-tiled bf16 layout (unchanged): frag for (16-row group g, k-chunk k, lane)
// at ushort offset (g*8 + k)*512 + lane*8 -> wave frag load = uniform base +
// lane*16B: one coalesced 1 KB dwordx4.
// ============================================================================

// ---------------- K1: slim prep — sqnorm, frag-tiled bf16 hi/lo split, M init ----
// grid MUST be 1024 x 256 (phase C uses exactly 4096 waves, one 16x32 tile each).
__global__ void prep_kernel(const float4* __restrict__ a,
                            float* __restrict__ sq,
                            ushort* __restrict__ Ehi, ushort* __restrict__ Elo,
                            unsigned long long* __restrict__ M) {
    const int gsz = gridDim.x * blockDim.x;          // 262144, multiple of 64
    const int g0 = blockIdx.x * blockDim.x + threadIdx.x;
    const int total = N * D / 4;                     // 524288 float4

    // phase A: per-row sqnorm (one row per wave per iter: 64 float4 = 1 row)
    for (int idx = g0; idx < total; idx += gsz) {
        float4 v = a[idx];
        float s = v.x * v.x + v.y * v.y + v.z * v.z + v.w * v.w;
        #pragma unroll
        for (int off = 32; off; off >>= 1) s += __shfl_down(s, off);
        if ((threadIdx.x & 63) == 0) sq[idx >> 6] = s;
    }

    // phase C: frag-tiled hi/lo split. One wave per (r16, ktc) tile of 16 rows x 32 k.
    {
        const int w = g0 >> 6;           // global wave id, 0..4095
        if (w < 4096) {
            const int lane = threadIdx.x & 63;
            const int tx = lane & 15;
            const int q  = lane >> 4;
            const int r16 = w >> 3;      // 0..511
            const int ktc = w & 7;       // 0..7
            const int row = r16 * 16 + tx;
            const float4 v0 = a[row * 64 + ktc * 8 + q * 2];
            const float4 v1 = a[row * 64 + ktc * 8 + q * 2 + 1];
            float e[8] = {v0.x, v0.y, v0.z, v0.w, v1.x, v1.y, v1.z, v1.w};
            short8 hs, ls;
            #pragma unroll
            for (int j = 0; j < 8; j++) {
                ushort h = f2bf(e[j]);
                ushort l = f2bf(e[j] - bf2f(h));
                hs[j] = (short)h;
                ls[j] = (short)l;
            }
            const size_t off = (size_t)(r16 * 8 + ktc) * 512 + lane * 8;
            *(short8*)&Ehi[off] = hs;
            *(short8*)&Elo[off] = ls;
        }
    }
    // M init
    for (int i = g0; i < N; i += gsz) M[i] = 0xFFFFFFFFFFFFFFFFull;
}

// ---------------- K2: round-9 optimum (verified 96.4us) + int4 hostAp ----------
// 128x64 tiles over tj>=2ti; per chunk: 12 batched loads -> sched_barrier ->
// 24 MFMAs -> sched_barrier; offsets +1024/chunk; band-group-of-16 enumeration
// (FETCH 16.6MB); 4 decoupled waves; minimal liveness (no spill, VGPR~64).
// Only delta vs r9/r11: hostAp via 4x int4 loads (verified in r12/r13).
__launch_bounds__(256, 4)
__global__ void argmin_sym(const ushort* __restrict__ Ehi, const ushort* __restrict__ Elo,
                           const int* __restrict__ host, const float* __restrict__ sq,
                           unsigned long long* __restrict__ M) {
    // XCD swizzle (4160 = 8*520, bijective)
    const int b0 = blockIdx.x;
    const int b = (b0 & 7) * (NBLK / 8) + (b0 >> 3);

    // decode b -> (band group g of 16 bands, column d, band-in-group i), tj-major
    int g, p;
    if (b < 1808)      { g = 0; p = b; }
    else if (b < 3104) { g = 1; p = b - 1808; }
    else if (b < 3888) { g = 2; p = b - 3104; }
    else               { g = 3; p = b - 3888; }
    int d, i;
    if (p >= 240) {
        d = 30 + ((p - 240) >> 4);
        i = (p - 240) & 15;
    } else {
        int m = (int)sqrtf((float)p);
        while (m * m > p) m--;
        while ((m + 1) * (m + 1) <= p) m++;
        if (p >= m * m + m) { d = 2 * m;     i = p - (m * m + m); }
        else                { d = 2 * m - 1; i = p - m * m; }
    }
    const int ti = 16 * g + i;
    const int tj = 32 * g + d;

    __shared__ float sqA_s[BIR];
    __shared__ float sqB_s[BJC];
    __shared__ int   hostB_s[BJC];
    __shared__ float rowV[2 * BIR]; __shared__ int rowI[2 * BIR];
    __shared__ float colV[2 * BJC]; __shared__ int colI[2 * BJC];

    const int ib0 = ti * BIR;
    const int jb0 = tj * BJC;
    const int tid = threadIdx.x;
    const int lane = tid & 63;
    const int wave = tid >> 6;      // 0..3
    const int wrow = wave >> 1;     // 0..1  (64-row half)
    const int wcol = wave & 1;      // 0..1  (32-col half)
    const int tx = lane & 15;       // 0..15
    const int q  = lane >> 4;       // 0..3

    if (tid < BIR) sqA_s[tid] = sq[ib0 + tid];
    if (tid < BJC) {
        sqB_s[tid] = sq[jb0 + tid];
        hostB_s[tid] = host[jb0 + tid];
    }

    // hostA packed per rt: one int4 load per rt (verified r12/r13)
    unsigned hostAp[4];
    #pragma unroll
    for (int rt = 0; rt < 4; rt++) {
        const int4 hv = *(const int4*)&host[ib0 + wrow * 64 + rt * 16 + q * 4];
        hostAp[rt] = ((unsigned)hv.x & 0xFFu) | (((unsigned)hv.y & 0xFFu) << 8) |
                     (((unsigned)hv.z & 0xFFu) << 16) | (((unsigned)hv.w & 0xFFu) << 24);
    }

    float4v acc[4][2];   // [rt][ct] — 32 f32/lane
    #pragma unroll
    for (int rt = 0; rt < 4; rt++)
        #pragma unroll
        for (int ct = 0; ct < 2; ct++) acc[rt][ct] = (float4v)(0.0f);

    const int pA = (ib0 >> 4) + wrow * 4;   // + rt (0..3)
    const int pB = (jb0 >> 4) + wcol * 2;   // + ct (0..1)
    const int lo8 = lane * 8;

    int obA[4], obB[2];
    #pragma unroll
    for (int rt = 0; rt < 4; rt++) obA[rt] = (((pA + rt) * 8) * 512 + lo8) * 2;
    #pragma unroll
    for (int ct = 0; ct < 2; ct++) obB[ct] = (((pB + ct) * 8) * 512 + lo8) * 2;
    const char* EhiB = (const char*)Ehi;
    const char* EloB = (const char*)Elo;

    short8 aH[4], aL[4], bH[2], bL[2];

    #pragma unroll
    for (int k = 0; k < 8; k++) {
        #pragma unroll
        for (int rt = 0; rt < 4; rt++) {
            aH[rt] = *(const short8*)(EhiB + obA[rt]);
            aL[rt] = *(const short8*)(EloB + obA[rt]);
        }
        #pragma unroll
        for (int ct = 0; ct < 2; ct++) {
            bH[ct] = *(const short8*)(EhiB + obB[ct]);
            bL[ct] = *(const short8*)(EloB + obB[ct]);
        }
        #pragma unroll
        for (int rt = 0; rt < 4; rt++) obA[rt] += 1024;
        #pragma unroll
        for (int ct = 0; ct < 2; ct++) obB[ct] += 1024;
        __builtin_amdgcn_sched_barrier(0);   // loads stay above, batched
        #pragma unroll
        for (int rt = 0; rt < 4; rt++)
            #pragma unroll
            for (int ct = 0; ct < 2; ct++)
                acc[rt][ct] = __builtin_amdgcn_mfma_f32_16x16x32_bf16(aH[rt], bH[ct], acc[rt][ct], 0, 0, 0);
        #pragma unroll
        for (int rt = 0; rt < 4; rt++)
            #pragma unroll
            for (int ct = 0; ct < 2; ct++)
                acc[rt][ct] = __builtin_amdgcn_mfma_f32_16x16x32_bf16(aH[rt], bL[ct], acc[rt][ct], 0, 0, 0);
        #pragma unroll
        for (int rt = 0; rt < 4; rt++)
            #pragma unroll
            for (int ct = 0; ct < 2; ct++)
                acc[rt][ct] = __builtin_amdgcn_mfma_f32_16x16x32_bf16(aL[rt], bH[ct], acc[rt][ct], 0, 0, 0);
        __builtin_amdgcn_sched_barrier(0);   // next chunk's loads may not hoist above
    }

    // ---- epilogue: dual-sided argmin (identical to rounds 5/8/9/11, verified) ----
    __syncthreads();

    #pragma unroll
    for (int rt = 0; rt < 4; rt++) {
        unsigned hp = hostAp[rt];
        #pragma unroll
        for (int reg = 0; reg < 4; reg++) {
            int il = wrow * 64 + rt * 16 + q * 4 + reg;
            int ig = ib0 + il;
            int ha = (int)((hp >> (8 * reg)) & 0xFFu);
            float v = 3.0e38f; int ix = 0x7fffffff;
            #pragma unroll
            for (int ct = 0; ct < 2; ct++) {
                int jl = wcol * 32 + ct * 16 + tx;
                int jg = jb0 + jl;
                float key = sqB_s[jl] - 2.0f * acc[rt][ct][reg];
                bool masked = (hostB_s[jl] == ha) || (jg <= ig);   // strict upper: i<j only
                if (!masked && (key < v || (key == v && jg < ix))) { v = key; ix = jg; }
            }
            #pragma unroll
            for (int dd = 1; dd < 16; dd <<= 1) {
                float ov = __shfl_xor(v, dd);
                int   oi = __shfl_xor(ix, dd);
                if (ov < v || (ov == v && oi < ix)) { v = ov; ix = oi; }
            }
            if (tx == 0) { rowV[il * 2 + wcol] = v; rowI[il * 2 + wcol] = ix; }
        }
    }

    #pragma unroll
    for (int ct = 0; ct < 2; ct++) {
        int jl = wcol * 32 + ct * 16 + tx;
        int jg = jb0 + jl;
        int hb = hostB_s[jl];
        float v = 3.0e38f; int ix = 0x7fffffff;
        #pragma unroll
        for (int rt = 0; rt < 4; rt++) {
            unsigned hp = hostAp[rt];
            #pragma unroll
            for (int reg = 0; reg < 4; reg++) {
                int il = wrow * 64 + rt * 16 + q * 4 + reg;
                int ig = ib0 + il;
                bool masked = ((int)((hp >> (8 * reg)) & 0xFFu) == hb) || (ig >= jg);
                float key = sqA_s[il] - 2.0f * acc[rt][ct][reg];
                if (!masked && (key < v || (key == v && ig < ix))) { v = key; ix = ig; }
            }
        }
        #pragma unroll
        for (int dd = 16; dd < 64; dd <<= 1) {
            float ov = __shfl_xor(v, dd);
            int   oi = __shfl_xor(ix, dd);
            if (ov < v || (ov == v && oi < ix)) { v = ov; ix = oi; }
        }
        if (q == 0) { colV[jl * 2 + wrow] = v; colI[jl * 2 + wrow] = ix; }
    }

    __syncthreads();
    if (tid < BIR) {
        float v0 = rowV[tid * 2];     int x0 = rowI[tid * 2];
        float v1 = rowV[tid * 2 + 1]; int x1 = rowI[tid * 2 + 1];
        if (v1 < v0 || (v1 == v0 && x1 < x0)) { v0 = v1; x0 = x1; }
        atomicMin(&M[ib0 + tid], packKI(v0, x0));
    }
    if (tid < BJC) {
        float w0 = colV[tid * 2];     int y0 = colI[tid * 2];
        float w1 = colV[tid * 2 + 1]; int y1 = colI[tid * 2 + 1];
        if (w1 < w0 || (w1 == w0 && y1 < y0)) { w0 = w1; y0 = y1; }
        atomicMin(&M[jb0 + tid], packKI(w0, y0));
    }
}

// ---------------- K3: fused output — copy e_actv/e_ap rows + gather e_an ----------------
__global__ void finalize_kernel(const unsigned long long* __restrict__ M,
                                const float4* __restrict__ a, const float4* __restrict__ p,
                                float4* __restrict__ out) {
    const int row = blockIdx.x;
    const int t = threadIdx.x;   // 0..63
    const int o = row * 64 + t;
    const int idx = (int)(unsigned)(M[row] & 0xFFFFFFFFull);
    float4 v = a[idx * 64 + t];
    out[o] = a[o];                         // e_actv copy
    out[(N * 64) + o] = p[o];              // e_ap copy
    out[(2 * N * 64) + o] = v;             // e_an
}

extern "C" void kernel_launch(void* const* d_in, const int* in_sizes, int n_in,
                              void* d_out, int out_size, void* d_ws, size_t ws_size,
                              hipStream_t stream) {
    const float* e_actv = (const float*)d_in[0];
    const float* e_ap   = (const float*)d_in[1];
    const int*   host   = (const int*)d_in[2];
    float* out = (float*)d_out;

    // workspace: M u64[N] | sq f32[N] | Ehi bf16[N*D] | Elo bf16[N*D]  (~8.3 MB)
    unsigned long long* M = (unsigned long long*)d_ws;
    float*  sq  = (float*)(M + N);
    ushort* Ehi = (ushort*)(sq + N);
    ushort* Elo = Ehi + (size_t)N * D;

    prep_kernel<<<1024, 256, 0, stream>>>(
        (const float4*)e_actv, sq, Ehi, Elo, M);
    argmin_sym<<<NBLK, 256, 0, stream>>>(Ehi, Elo, host, sq, M);
    finalize_kernel<<<N, 64, 0, stream>>>(
        M, (const float4*)e_actv, (const float4*)e_ap, (float4*)out);
}